// Round 1
// baseline (116.806 us; speedup 1.0000x reference)
//
#include <hip/hip_runtime.h>
#include <math.h>

#define BOUNDF 10.0f
#define EPSF 1e-6f
#define MIN_SCALEF 1e-4f
#define DD 1024
#define KK 64
#define KP1 65

#define TD 64    // dims per block
#define TR 128   // rows per block

// ---------------------------------------------------------------------------
// Kernel 1: per-dim spline tables.  One block (64 threads = 1 wave) per dim.
//   xk,yk: (D,65) knot positions; sl: (D,65) softplus slopes; scale: (D,)
// ---------------------------------------------------------------------------
__global__ __launch_bounds__(64) void rqs_precompute(
    const float* __restrict__ raw_w, const float* __restrict__ raw_h,
    const float* __restrict__ raw_s, const float* __restrict__ log_scale,
    float* __restrict__ xk, float* __restrict__ yk,
    float* __restrict__ sl, float* __restrict__ scale)
{
    const int d = blockIdx.x;
    const int k = threadIdx.x;  // 0..63

    float ew = __expf(raw_w[d * KK + k]);
    float eh = __expf(raw_h[d * KK + k]);

    // wave-wide sums (softmax denominators)
    float sw = ew, sh = eh;
#pragma unroll
    for (int off = 1; off < 64; off <<= 1) {
        sw += __shfl_xor(sw, off, 64);
        sh += __shfl_xor(sh, off, 64);
    }
    float wk = ew * (2.0f * BOUNDF) / sw;   // width_k
    float hk = eh * (2.0f * BOUNDF) / sh;   // height_k

    // inclusive prefix sums (cumsum)
    float cw = wk, ch = hk;
#pragma unroll
    for (int off = 1; off < 64; off <<= 1) {
        float tw = __shfl_up(cw, off, 64);
        float th = __shfl_up(ch, off, 64);
        if (k >= off) { cw += tw; ch += th; }
    }
    xk[d * KP1 + k + 1] = -BOUNDF + cw;
    yk[d * KP1 + k + 1] = -BOUNDF + ch;

    // slopes: softplus of 65 raw values (thread 0 covers the 65th)
    float rs = raw_s[d * KP1 + k];
    sl[d * KP1 + k] = log1pf(__expf(rs));
    if (k == 0) {
        xk[d * KP1] = -BOUNDF;
        yk[d * KP1] = -BOUNDF;
        float rs2 = raw_s[d * KP1 + KK];
        sl[d * KP1 + KK] = log1pf(__expf(rs2));
        scale[d] = log1pf(__expf(log_scale[d])) + MIN_SCALEF;
    }
}

// ---------------------------------------------------------------------------
// Kernel 2: main transform.  Block = 256 threads, tile = TD dims x TR rows.
// Tables for the block's 64 dims live in LDS; u/out accesses are float4
// coalesced (thread t -> dims 4*(t&15)..+3 of row (t>>4)).
// ---------------------------------------------------------------------------
__global__ __launch_bounds__(256) void rqs_main(
    const float* __restrict__ u, const float* __restrict__ tau,
    const float* __restrict__ bias,
    const float* __restrict__ xk_g, const float* __restrict__ yk_g,
    const float* __restrict__ sl_g, const float* __restrict__ scale_g,
    float* __restrict__ out)
{
    __shared__ float lxk[TD * KP1];
    __shared__ float lyk[TD * KP1];
    __shared__ float lsl[TD * KP1];

    const int bx = blockIdx.x;
    const int dchunk = bx & (DD / TD - 1);   // 16 d-chunks
    const int rchunk = bx >> 4;
    const int d0 = dchunk * TD;
    const int r0 = rchunk * TR;
    const int t = threadIdx.x;

    // stage tables: 64*65 floats per array, coalesced
    for (int i = t; i < TD * KP1; i += 256) {
        lxk[i] = xk_g[d0 * KP1 + i];
        lyk[i] = yk_g[d0 * KP1 + i];
        lsl[i] = sl_g[d0 * KP1 + i];
    }
    __syncthreads();

    const int g = t & 15;       // dim group (4 dims each)
    const int rlane = t >> 4;   // row within 16-row slab
    const int dl = g * 4;       // local dim base
    const int dg = d0 + dl;     // global dim base

    float sc[4], bi[4];
#pragma unroll
    for (int j = 0; j < 4; ++j) {
        sc[j] = scale_g[dg + j];
        bi[j] = bias[dg + j];
    }

#pragma unroll 1
    for (int it = 0; it < TR / 16; ++it) {
        const int b = r0 + it * 16 + rlane;
        const float4 uu = *(const float4*)(u + (size_t)b * DD + dg);
        const float tb = tau[b];
        float ua[4] = {uu.x, uu.y, uu.z, uu.w};
        float res[4];
#pragma unroll
        for (int j = 0; j < 4; ++j) {
            float uv = fminf(fmaxf(ua[j], EPSF), 1.0f - EPSF);
            float z = __logf(uv) - __logf(1.0f - uv);
            float zc = fminf(fmaxf(z, -BOUNDF), BOUNDF);
            const int base = (dl + j) * KP1;
            // branchless binary search: largest lo in [0,63] with xk[lo] <= zc
            int lo = 0;
#pragma unroll
            for (int s = 32; s >= 1; s >>= 1) {
                lo += (lxk[base + lo + s] <= zc) ? s : 0;
            }
            float x0 = lxk[base + lo], x1 = lxk[base + lo + 1];
            float y0 = lyk[base + lo], y1 = lyk[base + lo + 1];
            float s0 = lsl[base + lo], s1 = lsl[base + lo + 1];
            float w = x1 - x0, h = y1 - y0;
            float invw = __builtin_amdgcn_rcpf(w);
            float th = (zc - x0) * invw;
            float sm = h * invw;                       // s = h/w
            float t1m = th * (1.0f - th);
            float den = fmaf(fmaf(-2.0f, sm, s0 + s1), t1m, sm);
            float num = h * fmaf(sm * th, th, s0 * t1m);
            float y = fmaf(num, __builtin_amdgcn_rcpf(den), y0);
            y = (z > -BOUNDF && z < BOUNDF) ? y : z;   // passthrough outside
            res[j] = tb * fmaf(y, sc[j], bi[j]);
        }
        float4 ro = make_float4(res[0], res[1], res[2], res[3]);
        *(float4*)(out + (size_t)b * DD + dg) = ro;
    }
}

// ---------------------------------------------------------------------------
extern "C" void kernel_launch(void* const* d_in, const int* in_sizes, int n_in,
                              void* d_out, int out_size, void* d_ws, size_t ws_size,
                              hipStream_t stream)
{
    const float* u         = (const float*)d_in[0];
    const float* tau       = (const float*)d_in[1];
    const float* log_scale = (const float*)d_in[2];
    const float* bias      = (const float*)d_in[3];
    const float* raw_w     = (const float*)d_in[4];
    const float* raw_h     = (const float*)d_in[5];
    const float* raw_s     = (const float*)d_in[6];
    float* out = (float*)d_out;

    float* ws    = (float*)d_ws;           // needs ~803 KB
    float* xk    = ws;
    float* yk    = xk + DD * KP1;
    float* sl    = yk + DD * KP1;
    float* scale = sl + DD * KP1;

    const int B = in_sizes[0] / DD;        // 8192

    rqs_precompute<<<DD, 64, 0, stream>>>(raw_w, raw_h, raw_s, log_scale,
                                          xk, yk, sl, scale);
    rqs_main<<<(DD / TD) * (B / TR), 256, 0, stream>>>(u, tau, bias,
                                                       xk, yk, sl, scale, out);
}

// Round 2
// 111.014 us; speedup vs baseline: 1.0522x; 1.0522x over previous
//
#include <hip/hip_runtime.h>
#include <math.h>

#define BOUNDF 10.0f
#define EPSF 1e-6f
#define MIN_SCALEF 1e-4f
#define DD 1024
#define KK 64
#define KP1 65

#define TD 32    // dims per block  (LDS = 3*32*65*4 B = 24.96 KB -> 6 blocks/CU)
#define TR 128   // rows per block

// ---------------------------------------------------------------------------
// Kernel 1: per-dim spline tables.  One block (64 threads = 1 wave) per dim.
//   xk,yk: (D,65) knot positions; sl: (D,65) softplus slopes; scale: (D,)
// ---------------------------------------------------------------------------
__global__ __launch_bounds__(64) void rqs_precompute(
    const float* __restrict__ raw_w, const float* __restrict__ raw_h,
    const float* __restrict__ raw_s, const float* __restrict__ log_scale,
    float* __restrict__ xk, float* __restrict__ yk,
    float* __restrict__ sl, float* __restrict__ scale)
{
    const int d = blockIdx.x;
    const int k = threadIdx.x;  // 0..63

    float ew = __expf(raw_w[d * KK + k]);
    float eh = __expf(raw_h[d * KK + k]);

    // wave-wide sums (softmax denominators)
    float sw = ew, sh = eh;
#pragma unroll
    for (int off = 1; off < 64; off <<= 1) {
        sw += __shfl_xor(sw, off, 64);
        sh += __shfl_xor(sh, off, 64);
    }
    float wk = ew * (2.0f * BOUNDF) / sw;   // width_k
    float hk = eh * (2.0f * BOUNDF) / sh;   // height_k

    // inclusive prefix sums (cumsum)
    float cw = wk, ch = hk;
#pragma unroll
    for (int off = 1; off < 64; off <<= 1) {
        float tw = __shfl_up(cw, off, 64);
        float th = __shfl_up(ch, off, 64);
        if (k >= off) { cw += tw; ch += th; }
    }
    xk[d * KP1 + k + 1] = -BOUNDF + cw;
    yk[d * KP1 + k + 1] = -BOUNDF + ch;

    // slopes: softplus of 65 raw values (thread 0 covers the 65th)
    float rs = raw_s[d * KP1 + k];
    sl[d * KP1 + k] = log1pf(__expf(rs));
    if (k == 0) {
        xk[d * KP1] = -BOUNDF;
        yk[d * KP1] = -BOUNDF;
        float rs2 = raw_s[d * KP1 + KK];
        sl[d * KP1 + KK] = log1pf(__expf(rs2));
        scale[d] = log1pf(__expf(log_scale[d])) + MIN_SCALEF;
    }
}

// ---------------------------------------------------------------------------
// Kernel 2: main transform.  Block = 256 threads, tile = TD(32) dims x TR(128)
// rows.  Tables for the block's 32 dims live in LDS (25 KB -> 6 blocks/CU,
// 24 waves/CU).  Search levels 1-3 (knots 8,16,...,56) are cached in VGPRs so
// only the last 3 search steps touch LDS.  u/out accesses are float4
// coalesced (thread t -> dims 4*(t&7)..+3 of row (t>>3)).
// ---------------------------------------------------------------------------
__global__ __launch_bounds__(256, 6) void rqs_main(
    const float* __restrict__ u, const float* __restrict__ tau,
    const float* __restrict__ bias,
    const float* __restrict__ xk_g, const float* __restrict__ yk_g,
    const float* __restrict__ sl_g, const float* __restrict__ scale_g,
    float* __restrict__ out)
{
    __shared__ float lxk[TD * KP1];
    __shared__ float lyk[TD * KP1];
    __shared__ float lsl[TD * KP1];

    const int bx = blockIdx.x;
    const int dchunk = bx & (DD / TD - 1);   // 32 d-chunks (fast index ->
    const int rchunk = bx >> 5;              //  consecutive blocks stream rows)
    const int d0 = dchunk * TD;
    const int r0 = rchunk * TR;
    const int t = threadIdx.x;

    // stage tables: 32*65 floats per array, coalesced
    for (int i = t; i < TD * KP1; i += 256) {
        lxk[i] = xk_g[d0 * KP1 + i];
        lyk[i] = yk_g[d0 * KP1 + i];
        lsl[i] = sl_g[d0 * KP1 + i];
    }
    __syncthreads();

    const int g = t & 7;        // dim group (4 dims each, 8 groups)
    const int rlane = t >> 3;   // row within 32-row slab
    const int dl = g * 4;       // local dim base
    const int dg = d0 + dl;     // global dim base

    float sc[4], bi[4];
    float kreg[4][7];           // xk[8],xk[16],...,xk[56] per dim
#pragma unroll
    for (int j = 0; j < 4; ++j) {
        sc[j] = scale_g[dg + j];
        bi[j] = bias[dg + j];
        const int base = (dl + j) * KP1;
#pragma unroll
        for (int i = 0; i < 7; ++i) kreg[j][i] = lxk[base + 8 * (i + 1)];
    }

    // software-pipelined row loop: one u-load in flight during compute
    int b = r0 + rlane;
    float4 uu = *(const float4*)(u + (size_t)b * DD + dg);
    float tb = tau[b];

#pragma unroll 1
    for (int it = 0; it < TR / 32; ++it) {
        const int bcur = b;
        const float4 ucur = uu;
        const float tcur = tb;
        if (it + 1 < TR / 32) {
            const int bn = bcur + 32;
            uu = *(const float4*)(u + (size_t)bn * DD + dg);
            tb = tau[bn];
            b = bn;
        }
        float ua[4] = {ucur.x, ucur.y, ucur.z, ucur.w};
        float res[4];
#pragma unroll
        for (int j = 0; j < 4; ++j) {
            float uv = fminf(fmaxf(ua[j], EPSF), 1.0f - EPSF);
            // logit via single transcendental: log(u/(1-u))
            float z = __logf(uv * __builtin_amdgcn_rcpf(1.0f - uv));
            float zc = fminf(fmaxf(z, -BOUNDF), BOUNDF);
            const int base = (dl + j) * KP1;
            // search levels 1-3 from registers (cndmask trees, no LDS)
            int lo = (zc >= kreg[j][3]) ? 32 : 0;
            float m16 = (lo & 32) ? kreg[j][5] : kreg[j][1];
            lo += (zc >= m16) ? 16 : 0;
            float a8 = (lo & 32) ? kreg[j][4] : kreg[j][0];
            float b8 = (lo & 32) ? kreg[j][6] : kreg[j][2];
            float m8 = (lo & 16) ? b8 : a8;
            lo += (zc >= m8) ? 8 : 0;
            // last 3 steps in LDS
            lo += (lxk[base + lo + 4] <= zc) ? 4 : 0;
            lo += (lxk[base + lo + 2] <= zc) ? 2 : 0;
            lo += (lxk[base + lo + 1] <= zc) ? 1 : 0;
            float x0 = lxk[base + lo], x1 = lxk[base + lo + 1];
            float y0 = lyk[base + lo], y1 = lyk[base + lo + 1];
            float s0 = lsl[base + lo], s1 = lsl[base + lo + 1];
            float w = x1 - x0, h = y1 - y0;
            float invw = __builtin_amdgcn_rcpf(w);
            float th = (zc - x0) * invw;
            float sm = h * invw;                       // s = h/w
            float t1m = th * (1.0f - th);
            float den = fmaf(fmaf(-2.0f, sm, s0 + s1), t1m, sm);
            float num = h * fmaf(sm * th, th, s0 * t1m);
            float y = fmaf(num, __builtin_amdgcn_rcpf(den), y0);
            y = (z > -BOUNDF && z < BOUNDF) ? y : z;   // passthrough outside
            res[j] = tcur * fmaf(y, sc[j], bi[j]);
        }
        float4 ro = make_float4(res[0], res[1], res[2], res[3]);
        *(float4*)(out + (size_t)bcur * DD + dg) = ro;
    }
}

// ---------------------------------------------------------------------------
extern "C" void kernel_launch(void* const* d_in, const int* in_sizes, int n_in,
                              void* d_out, int out_size, void* d_ws, size_t ws_size,
                              hipStream_t stream)
{
    const float* u         = (const float*)d_in[0];
    const float* tau       = (const float*)d_in[1];
    const float* log_scale = (const float*)d_in[2];
    const float* bias      = (const float*)d_in[3];
    const float* raw_w     = (const float*)d_in[4];
    const float* raw_h     = (const float*)d_in[5];
    const float* raw_s     = (const float*)d_in[6];
    float* out = (float*)d_out;

    float* ws    = (float*)d_ws;           // needs ~803 KB
    float* xk    = ws;
    float* yk    = xk + DD * KP1;
    float* sl    = yk + DD * KP1;
    float* scale = sl + DD * KP1;

    const int B = in_sizes[0] / DD;        // 8192

    rqs_precompute<<<DD, 64, 0, stream>>>(raw_w, raw_h, raw_s, log_scale,
                                          xk, yk, sl, scale);
    rqs_main<<<(DD / TD) * (B / TR), 256, 0, stream>>>(u, tau, bias,
                                                       xk, yk, sl, scale, out);
}